// Round 12
// baseline (221.905 us; speedup 1.0000x reference)
//
#include <hip/hip_runtime.h>

typedef __bf16 bf16_t;
typedef __bf16 bf16x4 __attribute__((ext_vector_type(4)));
typedef __bf16 bf16x8 __attribute__((ext_vector_type(8)));
typedef float  floatx4 __attribute__((ext_vector_type(4)));
typedef unsigned long long u64;

#define MFMA16(a, b, c) __builtin_amdgcn_mfma_f32_16x16x32_bf16((a), (b), (c), 0, 0, 0)

// fp32 element offsets inside d_out
#define ADJ_OFF  2097152
#define MU_OFF   2162688
#define LV_OFF   4259840

#define TWO_LOG2E 2.8853900817779268f

// tanh(x) given argE2 = 2*log2(e)*x:  tanh = 1 - 2/(2^argE2 + 1).
__device__ __forceinline__ float fast_tanh2(float argE2) {
    float e = __builtin_amdgcn_exp2f(argE2);
    return 1.0f - 2.0f * __builtin_amdgcn_rcpf(e + 1.0f);
}

__device__ __forceinline__ bf16x8 cvt8(const float* p) {
    const floatx4 a = *(const floatx4*)p;
    const floatx4 b = *(const floatx4*)(p + 4);
    bf16x8 r;
#pragma unroll
    for (int j = 0; j < 4; j++) { r[j] = (bf16_t)a[j]; r[4 + j] = (bf16_t)b[j]; }
    return r;
}

// ---------------------------------------------------------------------------
// K0: prep, 465 blocks.
//  0-191:   32x32-tile transpose-cast of the 3 encoder weights.
//  192-199: wepack = bf16(Wemb*2log2e).   200-207: bepack.
//  208-463: adjacency row j = b-208 -> rowbits[j] (256-bit nz mask).
//  464:     wg1pk = Wg1 prepacked into MFMA B-fragment layout (4 KB).
// ---------------------------------------------------------------------------
__global__ __launch_bounds__(256) void k_prep(
    const float* __restrict__ We, const float* __restrict__ Wm,
    const float* __restrict__ Wl, const float* __restrict__ Wemb,
    const float* __restrict__ bemb, const float* __restrict__ gp,
    const int* __restrict__ iterp, const float* __restrict__ Wg1,
    bf16_t* __restrict__ Wt, bf16_t* __restrict__ wepack,
    bf16_t* __restrict__ bepack, u64* __restrict__ rowbits,
    bf16_t* __restrict__ wg1pk) {
    __shared__ float tile[32][33];
    const int b = blockIdx.x, tid = threadIdx.x;
    if (b < 192) {
        const int m = b >> 6, t6 = b & 63;
        const int K0 = (t6 >> 3) << 5, N0 = (t6 & 7) << 5;
        const float* src = (m == 0) ? We : ((m == 1) ? Wm : Wl);
#pragma unroll
        for (int p = 0; p < 4; p++) {
            const int idx = p * 256 + tid;
            tile[idx >> 5][idx & 31] = src[(K0 + (idx >> 5)) * 256 + N0 + (idx & 31)];
        }
        __syncthreads();
        bf16_t* dst = Wt + m * 65536;
#pragma unroll
        for (int p = 0; p < 4; p++) {
            const int idx = p * 256 + tid;
            const int nn = idx >> 5, kk = idx & 31;
            dst[(N0 + nn) * 256 + K0 + kk] = (bf16_t)tile[kk][nn];
        }
    } else if (b < 200) {
        const int base = (b - 192) * 2048;
#pragma unroll
        for (int p = 0; p < 8; p++) {
            const int idx = base + p * 256 + tid;
            wepack[idx] = (bf16_t)(TWO_LOG2E * Wemb[idx]);
        }
    } else if (b < 208) {
        const int base = (b - 200) * 2048;
#pragma unroll
        for (int p = 0; p < 8; p++) {
            const int idx = base + p * 256 + tid;
            bepack[idx] = (bf16_t)(TWO_LOG2E * bemb[idx]);
        }
    } else if (b < 464) {
        const int j = b - 208;
        const bool thr = (*iterp) > 50;
        float g = 1.0f / (1.0f + expf(-gp[j * 256 + tid]));
        if (tid == j) g = 1.0f;
        if (thr && !(g > 0.1f)) g = 0.0f;
        const u64 bal = __ballot(g != 0.0f);
        if ((tid & 63) == 0) rowbits[j * 4 + (tid >> 6)] = bal;
    } else {
        // wg1pk[((ks*2+te)*16+n)*32 + q*8 + j] = Wg1[(ks*32+q*8+j)*32+te*16+n]
#pragma unroll
        for (int idx = tid; idx < 2048; idx += 256) {
            const int jj = idx & 7, qq = (idx >> 3) & 3, nn = (idx >> 5) & 15;
            const int te = (idx >> 9) & 1, ks = (idx >> 10) & 1;
            wg1pk[idx] = (bf16_t)Wg1[(ks * 32 + qq * 8 + jj) * 32 + te * 16 + nn];
        }
    }
}

// ---------------------------------------------------------------------------
// K_mid: merged encoder (blocks 0-127, 64-row bands) + M-build (blocks
// 128-255, 2 adjacency rows each).  The two halves are independent; merging
// saves a launch and runs them concurrently.
// ---------------------------------------------------------------------------
__global__ __launch_bounds__(512) void k_mid(
    const float* __restrict__ X, const bf16_t* __restrict__ Wt,
    const float* __restrict__ benc, const float* __restrict__ bmu,
    const float* __restrict__ blv, float* __restrict__ MuOut,
    float* __restrict__ LvOut, const float* __restrict__ gp,
    const int* __restrict__ iterp, const u64* __restrict__ rowbits,
    bf16_t* __restrict__ Mb, float* __restrict__ adjOut) {
    __shared__ __align__(16) bf16_t Xs[64 * 264];
    __shared__ __align__(16) bf16_t Hs[64 * 264];
    const int tid = threadIdx.x;

    if (blockIdx.x >= 128) {
        // ---- M-build: j = (b-128)*2 + (tid>>8), col = tid&255 ----
        u64* bits = (u64*)Xs;                      // 8 KB alias
        const int jb = (blockIdx.x - 128) * 2;
#pragma unroll
        for (int p = 0; p < 2; p++) {
            const int idx = p * 512 + tid;
            bits[idx] = rowbits[idx];
        }
        __syncthreads();
        const int sub = tid >> 8, col = tid & 255;
        const int j = jb + sub;
        const int w64 = col >> 6, sh = col & 63;   // w64 wave-uniform
        int cnt = 0;
#pragma unroll 8
        for (int jp = 0; jp < 256; jp++)
            cnt += (int)((bits[jp * 4 + w64] >> sh) & 1ull);
        const int rc = (int)(__popcll(bits[j * 4 + 0]) + __popcll(bits[j * 4 + 1]) +
                             __popcll(bits[j * 4 + 2]) + __popcll(bits[j * 4 + 3]));
        const float rso = rsqrtf((float)(rc < 1 ? 1 : rc));
        const float rsi = rsqrtf((float)(cnt < 1 ? 1 : cnt));
        float g = 1.0f / (1.0f + expf(-gp[j * 256 + col]));
        if (col == j) g = 1.0f;
        if ((*iterp) > 50 && !(g > 0.1f)) g = 0.0f;
        if (adjOut) adjOut[j * 256 + col] = g;
        Mb[col * 256 + j] = (bf16_t)(g * rso * rsi);
        return;
    }

    // ---- encoder: 64-row band ----
    const bf16_t* Bte = Wt;
    const bf16_t* Btm = Wt + 65536;
    const bf16_t* Btl = Wt + 131072;
    const int r0 = blockIdx.x * 64;
    const int w = tid >> 6;
    const int lane = tid & 63;
    const int n = lane & 15, q = lane >> 4;
    const int cw = w * 32;
    const floatx4 z4 = {0.f, 0.f, 0.f, 0.f};

#pragma unroll
    for (int p = 0; p < 4; p++) {
        const int e0 = (p * 512 + tid) * 8;
        const int row = e0 >> 8, col = e0 & 255;
        *(bf16x8*)(Xs + row * 264 + col) = cvt8(X + (r0 + row) * 256 + col);
    }
    __syncthreads();

    // phase A: H = relu(Xs @ We + be)
    floatx4 ah[4][2];
#pragma unroll
    for (int rt = 0; rt < 4; rt++)
#pragma unroll
        for (int tc = 0; tc < 2; tc++) ah[rt][tc] = z4;
#pragma unroll 2
    for (int k0 = 0; k0 < 256; k0 += 32) {
        bf16x8 a[4], b[2];
#pragma unroll
        for (int rt = 0; rt < 4; rt++)
            a[rt] = *(const bf16x8*)(Xs + (rt * 16 + n) * 264 + k0 + q * 8);
#pragma unroll
        for (int tc = 0; tc < 2; tc++)
            b[tc] = *(const bf16x8*)(Bte + (cw + tc * 16 + n) * 256 + k0 + q * 8);
#pragma unroll
        for (int rt = 0; rt < 4; rt++)
#pragma unroll
            for (int tc = 0; tc < 2; tc++)
                ah[rt][tc] = MFMA16(a[rt], b[tc], ah[rt][tc]);
    }
#pragma unroll
    for (int tc = 0; tc < 2; tc++) {
        const int col = cw + tc * 16 + n;
        const float bv = benc[col];
#pragma unroll
        for (int rt = 0; rt < 4; rt++)
#pragma unroll
            for (int r = 0; r < 4; r++)
                Hs[(rt * 16 + q * 4 + r) * 264 + col] =
                    (bf16_t)fmaxf(ah[rt][tc][r] + bv, 0.0f);
    }
    __syncthreads();

    // phase B1: mu
    {
        floatx4 am[4][2];
#pragma unroll
        for (int rt = 0; rt < 4; rt++)
#pragma unroll
            for (int tc = 0; tc < 2; tc++) am[rt][tc] = z4;
#pragma unroll 2
        for (int k0 = 0; k0 < 256; k0 += 32) {
            bf16x8 a[4], bm_[2];
#pragma unroll
            for (int rt = 0; rt < 4; rt++)
                a[rt] = *(const bf16x8*)(Hs + (rt * 16 + n) * 264 + k0 + q * 8);
#pragma unroll
            for (int tc = 0; tc < 2; tc++)
                bm_[tc] = *(const bf16x8*)(Btm + (cw + tc * 16 + n) * 256 + k0 + q * 8);
#pragma unroll
            for (int rt = 0; rt < 4; rt++)
#pragma unroll
                for (int tc = 0; tc < 2; tc++)
                    am[rt][tc] = MFMA16(a[rt], bm_[tc], am[rt][tc]);
        }
#pragma unroll
        for (int tc = 0; tc < 2; tc++) {
            const int col = cw + tc * 16 + n;
            const float bmv = bmu[col];
#pragma unroll
            for (int rt = 0; rt < 4; rt++)
#pragma unroll
                for (int r = 0; r < 4; r++)
                    MuOut[(r0 + rt * 16 + q * 4 + r) * 256 + col] = am[rt][tc][r] + bmv;
        }
    }

    // phase B2: lv
    {
        floatx4 al[4][2];
#pragma unroll
        for (int rt = 0; rt < 4; rt++)
#pragma unroll
            for (int tc = 0; tc < 2; tc++) al[rt][tc] = z4;
#pragma unroll 2
        for (int k0 = 0; k0 < 256; k0 += 32) {
            bf16x8 a[4], bl_[2];
#pragma unroll
            for (int rt = 0; rt < 4; rt++)
                a[rt] = *(const bf16x8*)(Hs + (rt * 16 + n) * 264 + k0 + q * 8);
#pragma unroll
            for (int tc = 0; tc < 2; tc++)
                bl_[tc] = *(const bf16x8*)(Btl + (cw + tc * 16 + n) * 256 + k0 + q * 8);
#pragma unroll
            for (int rt = 0; rt < 4; rt++)
#pragma unroll
                for (int tc = 0; tc < 2; tc++)
                    al[rt][tc] = MFMA16(a[rt], bl_[tc], al[rt][tc]);
        }
#pragma unroll
        for (int tc = 0; tc < 2; tc++) {
            const int col = cw + tc * 16 + n;
            const float blvv = blv[col];
#pragma unroll
            for (int rt = 0; rt < 4; rt++)
#pragma unroll
                for (int r = 0; r < 4; r++)
                    LvOut[(r0 + rt * 16 + q * 4 + r) * 256 + col] = al[rt][tc][r] + blvv;
        }
    }
}

// ---------------------------------------------------------------------------
// K4: fused GCN v13 — Q-HALF-SPLIT for occupancy.  2048 blocks x 512 thr,
// 4 batch rows/block processed as two halves of 2 rows:
//   [phase1(half) -> barrier -> phase2+epilogue -> barrier] x 2.
// LDS 68.5 -> 36.8 KB: 2 -> 4 blocks/CU at the (compiler-chosen) 64-VGPR
// tier — doubles latency hiding for the VALU-issue-bound tanh chain.
// Per-phase register demand DROPS (acc[2][4] not [2][8]; wg1f reloaded
// per half from wg1pk, L1-hot) -> no spill risk under the same (512,4).
// Spill invariant: WRITE_SIZE == 8192 KB (rise => revert split).
// ---------------------------------------------------------------------------
__global__ __launch_bounds__(512, 4) void k_gcn(
    const float* __restrict__ Mu, const float* __restrict__ Lv,
    const float* __restrict__ Eps, const bf16_t* __restrict__ wepack,
    const bf16_t* __restrict__ bepack, const bf16_t* __restrict__ wg1pk,
    const float* __restrict__ bg1, const float* __restrict__ Wg2,
    const bf16_t* __restrict__ Mb, float* __restrict__ Vout) {
    __shared__ __align__(16) bf16_t smem[64 * 256];   // 32 KB: one half (2 bl)
    __shared__ float zs[1024];
    const int tid = threadIdx.x;
    const int lane = tid & 63;
    const int w = tid >> 6;                 // wave 0..7
    const int n = lane & 15, q = lane >> 4;
    const int bg = blockIdx.x;              // batch quad
    const floatx4 z4 = {0.f, 0.f, 0.f, 0.f};

    // stage z for 4 rows
    {
        const int gi = bg * 1024 + tid;
        zs[tid] = fmaf(Eps[gi], __expf(0.5f * Lv[gi]), Mu[gi]);
        const int gi2 = gi + 512;
        zs[tid + 512] = fmaf(Eps[gi2], __expf(0.5f * Lv[gi2]), Mu[gi2]);
    }
    __syncthreads();

    const float w2a = Wg2[n],  w2b = Wg2[16 + n];
    const float b1a = bg1[n],  b1b = bg1[16 + n];
    const int i0 = w * 32;
    const bool h0 = (lane & 1), h1_ = (lane & 2), h2 = (lane & 4), h3 = (lane & 8);

#pragma unroll
    for (int half = 0; half < 2; half++) {
        // wg1f: 4 vector loads from prepacked fragments (L1-hot 2nd half)
        bf16x8 wg1f[2][2];
#pragma unroll
        for (int ks = 0; ks < 2; ks++)
#pragma unroll
            for (int te = 0; te < 2; te++)
                wg1f[ks][te] = *(const bf16x8*)(wg1pk +
                    ((ks * 2 + te) * 16 + n) * 32 + q * 8);

        // ---- phase 1: wave w -> j-tiles {2w,2w+1}, bl in {half*2, half*2+1}
#pragma unroll
        for (int jt2 = 0; jt2 < 2; jt2++) {
            const int j0 = (w * 2 + jt2) * 16;
            const int jA = j0 + n;
            const bf16x8 we0 = *(const bf16x8*)(wepack + jA * 64 + q * 8);
            const bf16x8 we1 = *(const bf16x8*)(wepack + jA * 64 + 32 + q * 8);
            const bf16x8 be0 = *(const bf16x8*)(bepack + jA * 64 + q * 8);
            const bf16x8 be1 = *(const bf16x8*)(bepack + jA * 64 + 32 + q * 8);
            const int j8a = (j0 >> 3) + (q >> 1);
            const int jlo = (q & 1) * 4;
            const int sw = ((j8a ^ (n & 7)) << 3) + jlo;
#pragma unroll
            for (int blh = 0; blh < 2; blh++) {
                const float zv = zs[(half * 2 + blh) * 256 + jA];
                bf16x8 a0, a1;
#pragma unroll
                for (int j = 0; j < 8; j++) {
                    a0[j] = (bf16_t)fast_tanh2(fmaf(zv, (float)we0[j], (float)be0[j]));
                    a1[j] = (bf16_t)fast_tanh2(fmaf(zv, (float)we1[j], (float)be1[j]));
                }
                floatx4 c0 = z4, c1 = z4;
                c0 = MFMA16(a0, wg1f[0][0], c0);
                c0 = MFMA16(a1, wg1f[1][0], c0);
                c1 = MFMA16(a0, wg1f[0][1], c1);
                c1 = MFMA16(a1, wg1f[1][1], c1);
                bf16x4 s0, s1;
#pragma unroll
                for (int r = 0; r < 4; r++) { s0[r] = (bf16_t)c0[r]; s1[r] = (bf16_t)c1[r]; }
                *(bf16x4*)(smem + (blh * 32 + n) * 256 + sw) = s0;       // e = n
                *(bf16x4*)(smem + (blh * 32 + 16 + n) * 256 + sw) = s1;  // e = 16+n
            }
        }
        __syncthreads();

        // ---- phase 2: T1 = M @ Q_half (wave w: i in [i0,i0+32), c in [0,64))
        floatx4 acc[2][4];
#pragma unroll
        for (int ti = 0; ti < 2; ti++)
#pragma unroll
            for (int tc = 0; tc < 4; tc++) acc[ti][tc] = z4;
#pragma unroll
        for (int k0 = 0; k0 < 256; k0 += 32) {
            const int k8 = k0 >> 3;
            bf16x8 a[2], b[4];
#pragma unroll
            for (int ti = 0; ti < 2; ti++)
                a[ti] = *(const bf16x8*)(Mb + (i0 + ti * 16 + n) * 256 + k0 + q * 8);
#pragma unroll
            for (int tc = 0; tc < 4; tc++)
                b[tc] = *(const bf16x8*)(smem + (tc * 16 + n) * 256 +
                                         (((k8 + q) ^ (n & 7)) << 3));
            __builtin_amdgcn_s_setprio(1);
#pragma unroll
            for (int ti = 0; ti < 2; ti++)
#pragma unroll
                for (int tc = 0; tc < 4; tc++)
                    acc[ti][tc] = MFMA16(a[ti], b[tc], acc[ti][tc]);
            __builtin_amdgcn_s_setprio(0);
        }

        // ---- epilogue: relu+Wg2 contraction + 16-value reduce-scatter ----
        float v16[16];   // k = blh*8 + ti*4 + r
#pragma unroll
        for (int ti = 0; ti < 2; ti++)
#pragma unroll
            for (int r = 0; r < 4; r++) {
                v16[ti * 4 + r] =
                    fmaxf(acc[ti][0][r] + b1a, 0.0f) * w2a +
                    fmaxf(acc[ti][1][r] + b1b, 0.0f) * w2b;
                v16[8 + ti * 4 + r] =
                    fmaxf(acc[ti][2][r] + b1a, 0.0f) * w2a +
                    fmaxf(acc[ti][3][r] + b1b, 0.0f) * w2b;
            }
        float v8[8];
#pragma unroll
        for (int p = 0; p < 8; p++) {
            const float keep = h0 ? v16[2 * p + 1] : v16[2 * p];
            const float send = h0 ? v16[2 * p] : v16[2 * p + 1];
            v8[p] = keep + __shfl_xor(send, 1, 64);
        }
        float v4_[4];
#pragma unroll
        for (int p = 0; p < 4; p++) {
            const float keep = h1_ ? v8[2 * p + 1] : v8[2 * p];
            const float send = h1_ ? v8[2 * p] : v8[2 * p + 1];
            v4_[p] = keep + __shfl_xor(send, 2, 64);
        }
        float v2_[2];
#pragma unroll
        for (int p = 0; p < 2; p++) {
            const float keep = h2 ? v4_[2 * p + 1] : v4_[2 * p];
            const float send = h2 ? v4_[2 * p] : v4_[2 * p + 1];
            v2_[p] = keep + __shfl_xor(send, 4, 64);
        }
        {
            const float keep = h3 ? v2_[1] : v2_[0];
            const float send = h3 ? v2_[0] : v2_[1];
            const float vfin = keep + __shfl_xor(send, 8, 64);
            // lane holds k = n: r = n&3, ti = (n>>2)&1, blh = n>>3
            const int i_out = i0 + ((n >> 2) & 1) * 16 + q * 4 + (n & 3);
            Vout[bg * 1024 + (half * 2 + (n >> 3)) * 256 + i_out] = vfin;
        }
        if (half == 0) __syncthreads();   // reads done before half-1 stores
    }
}

// ---------------------------------------------------------------------------
// K5: x_hat = V @ M^T + b_g2, in place.  128 blocks, 64-row bands.
// ---------------------------------------------------------------------------
__global__ __launch_bounds__(512) void k_out(
    float* __restrict__ VX, const bf16_t* __restrict__ Mb,
    const float* __restrict__ bg2) {
    __shared__ __align__(16) bf16_t va[64 * 264];
    const int tid = threadIdx.x;
    const int lane = tid & 63;
    const int w = tid >> 6;                 // wave 0..7 -> col group
    const int n = lane & 15, q = lane >> 4;
    const int r0 = blockIdx.x * 64;

#pragma unroll
    for (int p = 0; p < 8; p++) {
        const int i4 = p * 512 + tid;
        const int row = i4 >> 6, c4 = (i4 & 63) * 4;
        const floatx4 v = *(const floatx4*)(VX + (r0 + row) * 256 + c4);
        bf16x4 s;
#pragma unroll
        for (int r = 0; r < 4; r++) s[r] = (bf16_t)v[r];
        *(bf16x4*)(va + row * 264 + c4) = s;
    }
    __syncthreads();

    const int cw = w * 32;
    const floatx4 z4 = {0.f, 0.f, 0.f, 0.f};
    floatx4 acc[4][2];
#pragma unroll
    for (int rt = 0; rt < 4; rt++)
#pragma unroll
        for (int tc = 0; tc < 2; tc++) acc[rt][tc] = z4;
#pragma unroll 2
    for (int k0 = 0; k0 < 256; k0 += 32) {
        bf16x8 a[4], b[2];
#pragma unroll
        for (int rt = 0; rt < 4; rt++)
            a[rt] = *(const bf16x8*)(va + (rt * 16 + n) * 264 + k0 + q * 8);
#pragma unroll
        for (int tc = 0; tc < 2; tc++)
            b[tc] = *(const bf16x8*)(Mb + (cw + tc * 16 + n) * 256 + k0 + q * 8);
#pragma unroll
        for (int rt = 0; rt < 4; rt++)
#pragma unroll
            for (int tc = 0; tc < 2; tc++)
                acc[rt][tc] = MFMA16(a[rt], b[tc], acc[rt][tc]);
    }
    const float bv = bg2[0];
#pragma unroll
    for (int tc = 0; tc < 2; tc++) {
        const int col = cw + tc * 16 + n;
#pragma unroll
        for (int rt = 0; rt < 4; rt++)
#pragma unroll
            for (int r = 0; r < 4; r++)
                VX[(r0 + rt * 16 + q * 4 + r) * 256 + col] = acc[rt][tc][r] + bv;
    }
}

// ---------------------------------------------------------------------------
// K6: restore the real adjacency (fp32) — fallback path only (no d_ws).
// ---------------------------------------------------------------------------
__global__ __launch_bounds__(256) void k_adj(
    const float* __restrict__ gp, const int* __restrict__ iterp,
    float* __restrict__ adjOut) {
    const int o = blockIdx.x * 256 + threadIdx.x;  // o = j*256 + i
    const int j = o >> 8, i = o & 255;
    float g = 1.0f / (1.0f + expf(-gp[o]));
    if (i == j) g = 1.0f;
    if ((*iterp) > 50 && !(g > 0.1f)) g = 0.0f;
    adjOut[o] = g;
}

// ---------------------------------------------------------------------------
extern "C" void kernel_launch(void* const* d_in, const int* in_sizes, int n_in,
                              void* d_out, int out_size, void* d_ws, size_t ws_size,
                              hipStream_t stream) {
    const float* x    = (const float*)d_in[0];
    const float* eps  = (const float*)d_in[1];
    const float* Wenc = (const float*)d_in[2];
    const float* benc = (const float*)d_in[3];
    const float* Wmu  = (const float*)d_in[4];
    const float* bmu  = (const float*)d_in[5];
    const float* Wlv  = (const float*)d_in[6];
    const float* blv  = (const float*)d_in[7];
    const float* gp   = (const float*)d_in[8];
    const float* Wemb = (const float*)d_in[9];
    const float* bemb = (const float*)d_in[10];
    const float* Wg1  = (const float*)d_in[11];
    const float* bg1  = (const float*)d_in[12];
    const float* Wg2  = (const float*)d_in[13];
    const float* bg2  = (const float*)d_in[14];
    const int*   itr  = (const int*)d_in[15];
    (void)in_sizes; (void)n_in; (void)out_size;

    float* xhat = (float*)d_out;             // [8192,256] fp32
    float* adjO = xhat + ADJ_OFF;            // [256,256]  fp32
    float* muo  = xhat + MU_OFF;             // [8192,256] fp32
    float* lvo  = xhat + LV_OFF;             // [8192,256] fp32

    // Scratch: Mb [0,128K) | wepack [128K,160K) | bepack [160K,192K) |
    // rowbits [192K,200K) | wg1pk [200K,204K).  Primary: d_ws (adj slot
    // free from the start -> k_mid writes adjO, no k_adj).  Fallback: adj
    // slot + k_adj last.  Wt (384 KB) at xhat byte 4 MB: dead after k_mid.
    const bool usews = (d_ws != nullptr && ws_size >= 262144);
    char* scr = usews ? (char*)d_ws : (char*)adjO;
    bf16_t* Mb      = (bf16_t*)scr;
    bf16_t* wepack  = (bf16_t*)(scr + 131072);
    bf16_t* bepack  = (bf16_t*)(scr + 163840);
    u64*    rowbits = (u64*)(scr + 196608);
    bf16_t* wg1pk   = (bf16_t*)(scr + 204800);
    bf16_t* Wt      = (bf16_t*)((char*)d_out + 4194304);

    k_prep<<<dim3(465), dim3(256), 0, stream>>>(Wenc, Wmu, Wlv, Wemb, bemb,
                                                gp, itr, Wg1, Wt, wepack,
                                                bepack, rowbits, wg1pk);
    k_mid <<<dim3(256), dim3(512), 0, stream>>>(x, Wt, benc, bmu, blv, muo,
                                                lvo, gp, itr, rowbits, Mb,
                                                usews ? adjO : nullptr);
    k_gcn <<<dim3(2048), dim3(512), 0, stream>>>(muo, lvo, eps, wepack, bepack,
                                                 wg1pk, bg1, Wg2, Mb, xhat);
    k_out <<<dim3(128), dim3(512), 0, stream>>>(xhat, Mb, bg2);
    if (!usews)
        k_adj<<<dim3(256), dim3(256), 0, stream>>>(gp, itr, adjO);
}

// Round 13
// 186.415 us; speedup vs baseline: 1.1904x; 1.1904x over previous
//
#include <hip/hip_runtime.h>

typedef __bf16 bf16_t;
typedef __bf16 bf16x4 __attribute__((ext_vector_type(4)));
typedef __bf16 bf16x8 __attribute__((ext_vector_type(8)));
typedef float  floatx4 __attribute__((ext_vector_type(4)));
typedef unsigned long long u64;

#define MFMA16(a, b, c) __builtin_amdgcn_mfma_f32_16x16x32_bf16((a), (b), (c), 0, 0, 0)

// fp32 element offsets inside d_out
#define ADJ_OFF  2097152
#define MU_OFF   2162688
#define LV_OFF   4259840

#define TWO_LOG2E 2.8853900817779268f

// tanh(x) given argE2 = 2*log2(e)*x:  tanh = 1 - 2/(2^argE2 + 1).
__device__ __forceinline__ float fast_tanh2(float argE2) {
    float e = __builtin_amdgcn_exp2f(argE2);
    return 1.0f - 2.0f * __builtin_amdgcn_rcpf(e + 1.0f);
}

__device__ __forceinline__ bf16x8 cvt8(const float* p) {
    const floatx4 a = *(const floatx4*)p;
    const floatx4 b = *(const floatx4*)(p + 4);
    bf16x8 r;
#pragma unroll
    for (int j = 0; j < 4; j++) { r[j] = (bf16_t)a[j]; r[4 + j] = (bf16_t)b[j]; }
    return r;
}

// ---------------------------------------------------------------------------
// K0: prep, 464 blocks.
//  0-191:   32x32-tile transpose-cast of the 3 encoder weights.
//  192-199: wepack = bf16(Wemb*2log2e).   200-207: bepack.
//  208-463: adjacency row j = b-208 -> rowbits[j] (256-bit nz mask).
// ---------------------------------------------------------------------------
__global__ __launch_bounds__(256) void k_prep(
    const float* __restrict__ We, const float* __restrict__ Wm,
    const float* __restrict__ Wl, const float* __restrict__ Wemb,
    const float* __restrict__ bemb, const float* __restrict__ gp,
    const int* __restrict__ iterp, bf16_t* __restrict__ Wt,
    bf16_t* __restrict__ wepack, bf16_t* __restrict__ bepack,
    u64* __restrict__ rowbits) {
    __shared__ float tile[32][33];
    const int b = blockIdx.x, tid = threadIdx.x;
    if (b < 192) {
        const int m = b >> 6, t6 = b & 63;
        const int K0 = (t6 >> 3) << 5, N0 = (t6 & 7) << 5;
        const float* src = (m == 0) ? We : ((m == 1) ? Wm : Wl);
#pragma unroll
        for (int p = 0; p < 4; p++) {
            const int idx = p * 256 + tid;
            tile[idx >> 5][idx & 31] = src[(K0 + (idx >> 5)) * 256 + N0 + (idx & 31)];
        }
        __syncthreads();
        bf16_t* dst = Wt + m * 65536;
#pragma unroll
        for (int p = 0; p < 4; p++) {
            const int idx = p * 256 + tid;
            const int nn = idx >> 5, kk = idx & 31;
            dst[(N0 + nn) * 256 + K0 + kk] = (bf16_t)tile[kk][nn];
        }
    } else if (b < 200) {
        const int base = (b - 192) * 2048;
#pragma unroll
        for (int p = 0; p < 8; p++) {
            const int idx = base + p * 256 + tid;
            wepack[idx] = (bf16_t)(TWO_LOG2E * Wemb[idx]);
        }
    } else if (b < 208) {
        const int base = (b - 200) * 2048;
#pragma unroll
        for (int p = 0; p < 8; p++) {
            const int idx = base + p * 256 + tid;
            bepack[idx] = (bf16_t)(TWO_LOG2E * bemb[idx]);
        }
    } else {
        const int j = b - 208;
        const bool thr = (*iterp) > 50;
        float g = 1.0f / (1.0f + expf(-gp[j * 256 + tid]));
        if (tid == j) g = 1.0f;
        if (thr && !(g > 0.1f)) g = 0.0f;
        const u64 bal = __ballot(g != 0.0f);
        if ((tid & 63) == 0) rowbits[j * 4 + (tid >> 6)] = bal;
    }
}

// ---------------------------------------------------------------------------
// K_mid: merged encoder (blocks 0-127, 64-row bands) + M-build (blocks
// 128-255, 2 adjacency rows each).  Independent halves run concurrently;
// saves a launch.  (Round-12 verified; non-gcn time 111 -> 103 us.)
// ---------------------------------------------------------------------------
__global__ __launch_bounds__(512) void k_mid(
    const float* __restrict__ X, const bf16_t* __restrict__ Wt,
    const float* __restrict__ benc, const float* __restrict__ bmu,
    const float* __restrict__ blv, float* __restrict__ MuOut,
    float* __restrict__ LvOut, const float* __restrict__ gp,
    const int* __restrict__ iterp, const u64* __restrict__ rowbits,
    bf16_t* __restrict__ Mb, float* __restrict__ adjOut) {
    __shared__ __align__(16) bf16_t Xs[64 * 264];
    __shared__ __align__(16) bf16_t Hs[64 * 264];
    const int tid = threadIdx.x;

    if (blockIdx.x >= 128) {
        // ---- M-build: j = (b-128)*2 + (tid>>8), col = tid&255 ----
        u64* bits = (u64*)Xs;                      // 8 KB alias
        const int jb = (blockIdx.x - 128) * 2;
#pragma unroll
        for (int p = 0; p < 2; p++) {
            const int idx = p * 512 + tid;
            bits[idx] = rowbits[idx];
        }
        __syncthreads();
        const int sub = tid >> 8, col = tid & 255;
        const int j = jb + sub;
        const int w64 = col >> 6, sh = col & 63;   // w64 wave-uniform
        int cnt = 0;
#pragma unroll 8
        for (int jp = 0; jp < 256; jp++)
            cnt += (int)((bits[jp * 4 + w64] >> sh) & 1ull);
        const int rc = (int)(__popcll(bits[j * 4 + 0]) + __popcll(bits[j * 4 + 1]) +
                             __popcll(bits[j * 4 + 2]) + __popcll(bits[j * 4 + 3]));
        const float rso = rsqrtf((float)(rc < 1 ? 1 : rc));
        const float rsi = rsqrtf((float)(cnt < 1 ? 1 : cnt));
        float g = 1.0f / (1.0f + expf(-gp[j * 256 + col]));
        if (col == j) g = 1.0f;
        if ((*iterp) > 50 && !(g > 0.1f)) g = 0.0f;
        if (adjOut) adjOut[j * 256 + col] = g;
        Mb[col * 256 + j] = (bf16_t)(g * rso * rsi);
        return;
    }

    // ---- encoder: 64-row band ----
    const bf16_t* Bte = Wt;
    const bf16_t* Btm = Wt + 65536;
    const bf16_t* Btl = Wt + 131072;
    const int r0 = blockIdx.x * 64;
    const int w = tid >> 6;
    const int lane = tid & 63;
    const int n = lane & 15, q = lane >> 4;
    const int cw = w * 32;
    const floatx4 z4 = {0.f, 0.f, 0.f, 0.f};

#pragma unroll
    for (int p = 0; p < 4; p++) {
        const int e0 = (p * 512 + tid) * 8;
        const int row = e0 >> 8, col = e0 & 255;
        *(bf16x8*)(Xs + row * 264 + col) = cvt8(X + (r0 + row) * 256 + col);
    }
    __syncthreads();

    // phase A: H = relu(Xs @ We + be)
    floatx4 ah[4][2];
#pragma unroll
    for (int rt = 0; rt < 4; rt++)
#pragma unroll
        for (int tc = 0; tc < 2; tc++) ah[rt][tc] = z4;
#pragma unroll 2
    for (int k0 = 0; k0 < 256; k0 += 32) {
        bf16x8 a[4], b[2];
#pragma unroll
        for (int rt = 0; rt < 4; rt++)
            a[rt] = *(const bf16x8*)(Xs + (rt * 16 + n) * 264 + k0 + q * 8);
#pragma unroll
        for (int tc = 0; tc < 2; tc++)
            b[tc] = *(const bf16x8*)(Bte + (cw + tc * 16 + n) * 256 + k0 + q * 8);
#pragma unroll
        for (int rt = 0; rt < 4; rt++)
#pragma unroll
            for (int tc = 0; tc < 2; tc++)
                ah[rt][tc] = MFMA16(a[rt], b[tc], ah[rt][tc]);
    }
#pragma unroll
    for (int tc = 0; tc < 2; tc++) {
        const int col = cw + tc * 16 + n;
        const float bv = benc[col];
#pragma unroll
        for (int rt = 0; rt < 4; rt++)
#pragma unroll
            for (int r = 0; r < 4; r++)
                Hs[(rt * 16 + q * 4 + r) * 264 + col] =
                    (bf16_t)fmaxf(ah[rt][tc][r] + bv, 0.0f);
    }
    __syncthreads();

    // phase B1: mu
    {
        floatx4 am[4][2];
#pragma unroll
        for (int rt = 0; rt < 4; rt++)
#pragma unroll
            for (int tc = 0; tc < 2; tc++) am[rt][tc] = z4;
#pragma unroll 2
        for (int k0 = 0; k0 < 256; k0 += 32) {
            bf16x8 a[4], bm_[2];
#pragma unroll
            for (int rt = 0; rt < 4; rt++)
                a[rt] = *(const bf16x8*)(Hs + (rt * 16 + n) * 264 + k0 + q * 8);
#pragma unroll
            for (int tc = 0; tc < 2; tc++)
                bm_[tc] = *(const bf16x8*)(Btm + (cw + tc * 16 + n) * 256 + k0 + q * 8);
#pragma unroll
            for (int rt = 0; rt < 4; rt++)
#pragma unroll
                for (int tc = 0; tc < 2; tc++)
                    am[rt][tc] = MFMA16(a[rt], bm_[tc], am[rt][tc]);
        }
#pragma unroll
        for (int tc = 0; tc < 2; tc++) {
            const int col = cw + tc * 16 + n;
            const float bmv = bmu[col];
#pragma unroll
            for (int rt = 0; rt < 4; rt++)
#pragma unroll
                for (int r = 0; r < 4; r++)
                    MuOut[(r0 + rt * 16 + q * 4 + r) * 256 + col] = am[rt][tc][r] + bmv;
        }
    }

    // phase B2: lv
    {
        floatx4 al[4][2];
#pragma unroll
        for (int rt = 0; rt < 4; rt++)
#pragma unroll
            for (int tc = 0; tc < 2; tc++) al[rt][tc] = z4;
#pragma unroll 2
        for (int k0 = 0; k0 < 256; k0 += 32) {
            bf16x8 a[4], bl_[2];
#pragma unroll
            for (int rt = 0; rt < 4; rt++)
                a[rt] = *(const bf16x8*)(Hs + (rt * 16 + n) * 264 + k0 + q * 8);
#pragma unroll
            for (int tc = 0; tc < 2; tc++)
                bl_[tc] = *(const bf16x8*)(Btl + (cw + tc * 16 + n) * 256 + k0 + q * 8);
#pragma unroll
            for (int rt = 0; rt < 4; rt++)
#pragma unroll
                for (int tc = 0; tc < 2; tc++)
                    al[rt][tc] = MFMA16(a[rt], bl_[tc], al[rt][tc]);
        }
#pragma unroll
        for (int tc = 0; tc < 2; tc++) {
            const int col = cw + tc * 16 + n;
            const float blvv = blv[col];
#pragma unroll
            for (int rt = 0; rt < 4; rt++)
#pragma unroll
                for (int r = 0; r < 4; r++)
                    LvOut[(r0 + rt * 16 + q * 4 + r) * 256 + col] = al[rt][tc][r] + blvv;
        }
    }
}

// ---------------------------------------------------------------------------
// K4: fused GCN v11 — EXACT round-9/11 version (79.5us verified).
// 2048 blocks x 512 thr, 4 batch rows/block, monolithic (round-12 lesson:
// Q-half-split doubled Mb re-reads + epilogues for zero occupancy gain,
// +50% time).  Spill invariant: WRITE_SIZE == 8192 KB.
// ---------------------------------------------------------------------------
__global__ __launch_bounds__(512, 4) void k_gcn(
    const float* __restrict__ Mu, const float* __restrict__ Lv,
    const float* __restrict__ Eps, const bf16_t* __restrict__ wepack,
    const bf16_t* __restrict__ bepack, const float* __restrict__ Wg1,
    const float* __restrict__ bg1, const float* __restrict__ Wg2,
    const bf16_t* __restrict__ Mb, float* __restrict__ Vout) {
    __shared__ __align__(16) bf16_t smem[128 * 256];   // 64 KB: 4 bl x 32 e
    __shared__ float zs[1024];
    const int tid = threadIdx.x;
    const int lane = tid & 63;
    const int w = tid >> 6;                 // wave 0..7
    const int n = lane & 15, q = lane >> 4;
    const int bg = blockIdx.x;              // batch quad
    const floatx4 z4 = {0.f, 0.f, 0.f, 0.f};

    // stage z for 4 rows (coalesced fp32 reads, 2 elems/thread)
    {
        const int gi = bg * 1024 + tid;
        zs[tid] = fmaf(Eps[gi], __expf(0.5f * Lv[gi]), Mu[gi]);
        const int gi2 = gi + 512;
        zs[tid + 512] = fmaf(Eps[gi2], __expf(0.5f * Lv[gi2]), Mu[gi2]);
    }

    // preload W_g1 B-fragments
    bf16x8 wg1f[2][2];
#pragma unroll
    for (int ks = 0; ks < 2; ks++)
#pragma unroll
        for (int te = 0; te < 2; te++)
#pragma unroll
            for (int j = 0; j < 8; j++)
                wg1f[ks][te][j] = (bf16_t)Wg1[(ks * 32 + q * 8 + j) * 32 + te * 16 + n];
    __syncthreads();

    // ---- phase 1: wave w -> j-tiles {2w, 2w+1}, each for bl 0..3 ----
#pragma unroll
    for (int jt2 = 0; jt2 < 2; jt2++) {
        const int j0 = (w * 2 + jt2) * 16;
        const int jA = j0 + n;
        const bf16x8 we0 = *(const bf16x8*)(wepack + jA * 64 + q * 8);
        const bf16x8 we1 = *(const bf16x8*)(wepack + jA * 64 + 32 + q * 8);
        const bf16x8 be0 = *(const bf16x8*)(bepack + jA * 64 + q * 8);
        const bf16x8 be1 = *(const bf16x8*)(bepack + jA * 64 + 32 + q * 8);
        float wf0[8], wf1[8], bf0[8], bf1[8];
#pragma unroll
        for (int j = 0; j < 8; j++) {
            wf0[j] = (float)we0[j]; wf1[j] = (float)we1[j];
            bf0[j] = (float)be0[j]; bf1[j] = (float)be1[j];
        }
        const int j8a = (j0 >> 3) + (q >> 1);
        const int jlo = (q & 1) * 4;
        const int sw = ((j8a ^ (n & 7)) << 3) + jlo;
#pragma unroll
        for (int bl = 0; bl < 4; bl++) {
            const float zv = zs[bl * 256 + jA];   // 2log2e folded into packs
            bf16x8 a0, a1;
#pragma unroll
            for (int j = 0; j < 8; j++) {
                a0[j] = (bf16_t)fast_tanh2(fmaf(zv, wf0[j], bf0[j]));
                a1[j] = (bf16_t)fast_tanh2(fmaf(zv, wf1[j], bf1[j]));
            }
            floatx4 c0 = z4, c1 = z4;
            c0 = MFMA16(a0, wg1f[0][0], c0);
            c0 = MFMA16(a1, wg1f[1][0], c0);
            c1 = MFMA16(a0, wg1f[0][1], c1);
            c1 = MFMA16(a1, wg1f[1][1], c1);
            bf16x4 s0, s1;
#pragma unroll
            for (int r = 0; r < 4; r++) { s0[r] = (bf16_t)c0[r]; s1[r] = (bf16_t)c1[r]; }
            *(bf16x4*)(smem + (bl * 32 + n) * 256 + sw) = s0;        // e = n
            *(bf16x4*)(smem + (bl * 32 + 16 + n) * 256 + sw) = s1;   // e = 16+n
        }
    }
    __syncthreads();

    // ---- phase 2: T1 = M @ Q (wave w: i in [w*32,w*32+32), c in [0,128)) --
    const int i0 = w * 32;
    floatx4 acc[2][8];
#pragma unroll
    for (int ti = 0; ti < 2; ti++)
#pragma unroll
        for (int tc = 0; tc < 8; tc++) acc[ti][tc] = z4;
#pragma unroll
    for (int k0 = 0; k0 < 256; k0 += 32) {
        const int k8 = k0 >> 3;
        bf16x8 a[2], b[8];
#pragma unroll
        for (int ti = 0; ti < 2; ti++)
            a[ti] = *(const bf16x8*)(Mb + (i0 + ti * 16 + n) * 256 + k0 + q * 8);
#pragma unroll
        for (int tc = 0; tc < 8; tc++)
            b[tc] = *(const bf16x8*)(smem + (tc * 16 + n) * 256 +
                                     (((k8 + q) ^ (n & 7)) << 3));
        __builtin_amdgcn_s_setprio(1);
#pragma unroll
        for (int ti = 0; ti < 2; ti++)
#pragma unroll
            for (int tc = 0; tc < 8; tc++)
                acc[ti][tc] = MFMA16(a[ti], b[tc], acc[ti][tc]);
        __builtin_amdgcn_s_setprio(0);
    }

    // ---- epilogue: in-register relu+Wg2 contraction + reduce-scatter ----
    const float w2a = Wg2[n],      w2b = Wg2[16 + n];
    const float b1a = bg1[n],      b1b = bg1[16 + n];
    float v32[32];   // k = bl*8 + ti*4 + r
#pragma unroll
    for (int bl = 0; bl < 4; bl++)
#pragma unroll
        for (int ti = 0; ti < 2; ti++)
#pragma unroll
            for (int r = 0; r < 4; r++)
                v32[bl * 8 + ti * 4 + r] =
                    fmaxf(acc[ti][2 * bl][r] + b1a, 0.0f) * w2a +
                    fmaxf(acc[ti][2 * bl + 1][r] + b1b, 0.0f) * w2b;
    const bool h0 = (lane & 1), h1_ = (lane & 2), h2 = (lane & 4), h3 = (lane & 8);
    float u16[16];
#pragma unroll
    for (int p = 0; p < 16; p++) {
        const float keep = h0 ? v32[2 * p + 1] : v32[2 * p];
        const float send = h0 ? v32[2 * p] : v32[2 * p + 1];
        u16[p] = keep + __shfl_xor(send, 1, 64);
    }
    float u8[8];
#pragma unroll
    for (int p = 0; p < 8; p++) {
        const float keep = h1_ ? u16[2 * p + 1] : u16[2 * p];
        const float send = h1_ ? u16[2 * p] : u16[2 * p + 1];
        u8[p] = keep + __shfl_xor(send, 2, 64);
    }
    float u4[4];
#pragma unroll
    for (int p = 0; p < 4; p++) {
        const float keep = h2 ? u8[2 * p + 1] : u8[2 * p];
        const float send = h2 ? u8[2 * p] : u8[2 * p + 1];
        u4[p] = keep + __shfl_xor(send, 4, 64);
    }
    float u2[2];
#pragma unroll
    for (int p = 0; p < 2; p++) {
        const float keep = h3 ? u4[2 * p + 1] : u4[2 * p];
        const float send = h3 ? u4[2 * p] : u4[2 * p + 1];
        u2[p] = keep + __shfl_xor(send, 8, 64);
    }
    {
        // lane holds k = 16*p + n: r = n&3, ti = (n>>2)&1, bl = p*2 + (n>>3)
        const int i_out = i0 + ((n >> 2) & 1) * 16 + q * 4 + (n & 3);
        const int blv = n >> 3;
        Vout[bg * 1024 + blv * 256 + i_out] = u2[0];
        Vout[bg * 1024 + (2 + blv) * 256 + i_out] = u2[1];
    }
}

// ---------------------------------------------------------------------------
// K5: x_hat = V @ M^T + b_g2, in place.  128 blocks, 64-row bands.
// ---------------------------------------------------------------------------
__global__ __launch_bounds__(512) void k_out(
    float* __restrict__ VX, const bf16_t* __restrict__ Mb,
    const float* __restrict__ bg2) {
    __shared__ __align__(16) bf16_t va[64 * 264];
    const int tid = threadIdx.x;
    const int lane = tid & 63;
    const int w = tid >> 6;                 // wave 0..7 -> col group
    const int n = lane & 15, q = lane >> 4;
    const int r0 = blockIdx.x * 64;

#pragma unroll
    for (int p = 0; p < 8; p++) {
        const int i4 = p * 512 + tid;
        const int row = i4 >> 6, c4 = (i4 & 63) * 4;
        const floatx4 v = *(const floatx4*)(VX + (r0 + row) * 256 + c4);
        bf16x4 s;
#pragma unroll
        for (int r = 0; r < 4; r++) s[r] = (bf16_t)v[r];
        *(bf16x4*)(va + row * 264 + c4) = s;
    }
    __syncthreads();

    const int cw = w * 32;
    const floatx4 z4 = {0.f, 0.f, 0.f, 0.f};
    floatx4 acc[4][2];
#pragma unroll
    for (int rt = 0; rt < 4; rt++)
#pragma unroll
        for (int tc = 0; tc < 2; tc++) acc[rt][tc] = z4;
#pragma unroll 2
    for (int k0 = 0; k0 < 256; k0 += 32) {
        bf16x8 a[4], b[2];
#pragma unroll
        for (int rt = 0; rt < 4; rt++)
            a[rt] = *(const bf16x8*)(va + (rt * 16 + n) * 264 + k0 + q * 8);
#pragma unroll
        for (int tc = 0; tc < 2; tc++)
            b[tc] = *(const bf16x8*)(Mb + (cw + tc * 16 + n) * 256 + k0 + q * 8);
#pragma unroll
        for (int rt = 0; rt < 4; rt++)
#pragma unroll
            for (int tc = 0; tc < 2; tc++)
                acc[rt][tc] = MFMA16(a[rt], b[tc], acc[rt][tc]);
    }
    const float bv = bg2[0];
#pragma unroll
    for (int tc = 0; tc < 2; tc++) {
        const int col = cw + tc * 16 + n;
#pragma unroll
        for (int rt = 0; rt < 4; rt++)
#pragma unroll
            for (int r = 0; r < 4; r++)
                VX[(r0 + rt * 16 + q * 4 + r) * 256 + col] = acc[rt][tc][r] + bv;
    }
}

// ---------------------------------------------------------------------------
// K6: restore the real adjacency (fp32) — fallback path only (no d_ws).
// ---------------------------------------------------------------------------
__global__ __launch_bounds__(256) void k_adj(
    const float* __restrict__ gp, const int* __restrict__ iterp,
    float* __restrict__ adjOut) {
    const int o = blockIdx.x * 256 + threadIdx.x;  // o = j*256 + i
    const int j = o >> 8, i = o & 255;
    float g = 1.0f / (1.0f + expf(-gp[o]));
    if (i == j) g = 1.0f;
    if ((*iterp) > 50 && !(g > 0.1f)) g = 0.0f;
    adjOut[o] = g;
}

// ---------------------------------------------------------------------------
extern "C" void kernel_launch(void* const* d_in, const int* in_sizes, int n_in,
                              void* d_out, int out_size, void* d_ws, size_t ws_size,
                              hipStream_t stream) {
    const float* x    = (const float*)d_in[0];
    const float* eps  = (const float*)d_in[1];
    const float* Wenc = (const float*)d_in[2];
    const float* benc = (const float*)d_in[3];
    const float* Wmu  = (const float*)d_in[4];
    const float* bmu  = (const float*)d_in[5];
    const float* Wlv  = (const float*)d_in[6];
    const float* blv  = (const float*)d_in[7];
    const float* gp   = (const float*)d_in[8];
    const float* Wemb = (const float*)d_in[9];
    const float* bemb = (const float*)d_in[10];
    const float* Wg1  = (const float*)d_in[11];
    const float* bg1  = (const float*)d_in[12];
    const float* Wg2  = (const float*)d_in[13];
    const float* bg2  = (const float*)d_in[14];
    const int*   itr  = (const int*)d_in[15];
    (void)in_sizes; (void)n_in; (void)out_size;

    float* xhat = (float*)d_out;             // [8192,256] fp32
    float* adjO = xhat + ADJ_OFF;            // [256,256]  fp32
    float* muo  = xhat + MU_OFF;             // [8192,256] fp32
    float* lvo  = xhat + LV_OFF;             // [8192,256] fp32

    // Scratch: Mb [0,128K) | wepack [128K,160K) | bepack [160K,192K) |
    // rowbits [192K,200K).  Primary: d_ws (adj slot free from the start ->
    // k_mid writes adjO, no k_adj).  Fallback: adj slot + k_adj last.
    // Wt (384 KB) at xhat byte 4 MB: dead after k_mid.
    const bool usews = (d_ws != nullptr && ws_size >= 262144);
    char* scr = usews ? (char*)d_ws : (char*)adjO;
    bf16_t* Mb      = (bf16_t*)scr;
    bf16_t* wepack  = (bf16_t*)(scr + 131072);
    bf16_t* bepack  = (bf16_t*)(scr + 163840);
    u64*    rowbits = (u64*)(scr + 196608);
    bf16_t* Wt      = (bf16_t*)((char*)d_out + 4194304);

    k_prep<<<dim3(464), dim3(256), 0, stream>>>(Wenc, Wmu, Wlv, Wemb, bemb,
                                                gp, itr, Wt, wepack, bepack,
                                                rowbits);
    k_mid <<<dim3(256), dim3(512), 0, stream>>>(x, Wt, benc, bmu, blv, muo,
                                                lvo, gp, itr, rowbits, Mb,
                                                usews ? adjO : nullptr);
    k_gcn <<<dim3(2048), dim3(512), 0, stream>>>(muo, lvo, eps, wepack, bepack,
                                                 Wg1, bg1, Wg2, Mb, xhat);
    k_out <<<dim3(128), dim3(512), 0, stream>>>(xhat, Mb, bg2);
    if (!usews)
        k_adj<<<dim3(256), dim3(256), 0, stream>>>(gp, itr, adjO);
}

// Round 15
// 185.257 us; speedup vs baseline: 1.1978x; 1.0063x over previous
//
#include <hip/hip_runtime.h>

typedef __bf16 bf16_t;
typedef __bf16 bf16x4 __attribute__((ext_vector_type(4)));
typedef __bf16 bf16x8 __attribute__((ext_vector_type(8)));
typedef float  floatx4 __attribute__((ext_vector_type(4)));
typedef unsigned long long u64;

#define MFMA16(a, b, c) __builtin_amdgcn_mfma_f32_16x16x32_bf16((a), (b), (c), 0, 0, 0)

// fp32 element offsets inside d_out
#define ADJ_OFF  2097152
#define MU_OFF   2162688
#define LV_OFF   4259840

#define TWO_LOG2E 2.8853900817779268f

// tanh(x) given argE2 = 2*log2(e)*x:  tanh = 1 - 2/(2^argE2 + 1).
__device__ __forceinline__ float fast_tanh2(float argE2) {
    float e = __builtin_amdgcn_exp2f(argE2);
    return 1.0f - 2.0f * __builtin_amdgcn_rcpf(e + 1.0f);
}

__device__ __forceinline__ bf16x8 cvt8(const float* p) {
    const floatx4 a = *(const floatx4*)p;
    const floatx4 b = *(const floatx4*)(p + 4);
    bf16x8 r;
#pragma unroll
    for (int j = 0; j < 4; j++) { r[j] = (bf16_t)a[j]; r[4 + j] = (bf16_t)b[j]; }
    return r;
}

// ---------------------------------------------------------------------------
// K0: prep, 464 blocks.
//  0-191:   32x32-tile transpose-cast of the 3 encoder weights.
//  192-199: wepack = bf16(Wemb*2log2e).   200-207: bepack.
//  208-463: adjacency row j = b-208 -> rowbits[j] (256-bit nz mask).
// ---------------------------------------------------------------------------
__global__ __launch_bounds__(256) void k_prep(
    const float* __restrict__ We, const float* __restrict__ Wm,
    const float* __restrict__ Wl, const float* __restrict__ Wemb,
    const float* __restrict__ bemb, const float* __restrict__ gp,
    const int* __restrict__ iterp, bf16_t* __restrict__ Wt,
    bf16_t* __restrict__ wepack, bf16_t* __restrict__ bepack,
    u64* __restrict__ rowbits) {
    __shared__ float tile[32][33];
    const int b = blockIdx.x, tid = threadIdx.x;
    if (b < 192) {
        const int m = b >> 6, t6 = b & 63;
        const int K0 = (t6 >> 3) << 5, N0 = (t6 & 7) << 5;
        const float* src = (m == 0) ? We : ((m == 1) ? Wm : Wl);
#pragma unroll
        for (int p = 0; p < 4; p++) {
            const int idx = p * 256 + tid;
            tile[idx >> 5][idx & 31] = src[(K0 + (idx >> 5)) * 256 + N0 + (idx & 31)];
        }
        __syncthreads();
        bf16_t* dst = Wt + m * 65536;
#pragma unroll
        for (int p = 0; p < 4; p++) {
            const int idx = p * 256 + tid;
            const int nn = idx >> 5, kk = idx & 31;
            dst[(N0 + nn) * 256 + K0 + kk] = (bf16_t)tile[kk][nn];
        }
    } else if (b < 200) {
        const int base = (b - 192) * 2048;
#pragma unroll
        for (int p = 0; p < 8; p++) {
            const int idx = base + p * 256 + tid;
            wepack[idx] = (bf16_t)(TWO_LOG2E * Wemb[idx]);
        }
    } else if (b < 208) {
        const int base = (b - 200) * 2048;
#pragma unroll
        for (int p = 0; p < 8; p++) {
            const int idx = base + p * 256 + tid;
            bepack[idx] = (bf16_t)(TWO_LOG2E * bemb[idx]);
        }
    } else {
        const int j = b - 208;
        const bool thr = (*iterp) > 50;
        float g = 1.0f / (1.0f + expf(-gp[j * 256 + tid]));
        if (tid == j) g = 1.0f;
        if (thr && !(g > 0.1f)) g = 0.0f;
        const u64 bal = __ballot(g != 0.0f);
        if ((tid & 63) == 0) rowbits[j * 4 + (tid >> 6)] = bal;
    }
}

// ---------------------------------------------------------------------------
// K_mid: merged encoder (blocks 0-127, 64-row bands) + M-build (blocks
// 128-255, 2 adjacency rows each).  Round-14 delta: mu & lv computed in ONE
// interleaved k-loop (16 MFMA/step x 8 steps instead of 2 sequential
// phases of 8 MFMA/step x 8) — halves phase-B's serial dependency chain
// at this kernel's low occupancy (2 waves/SIMD).  Regs ~100 < 128 tier.
// ---------------------------------------------------------------------------
__global__ __launch_bounds__(512) void k_mid(
    const float* __restrict__ X, const bf16_t* __restrict__ Wt,
    const float* __restrict__ benc, const float* __restrict__ bmu,
    const float* __restrict__ blv, float* __restrict__ MuOut,
    float* __restrict__ LvOut, const float* __restrict__ gp,
    const int* __restrict__ iterp, const u64* __restrict__ rowbits,
    bf16_t* __restrict__ Mb, float* __restrict__ adjOut) {
    __shared__ __align__(16) bf16_t Xs[64 * 264];
    __shared__ __align__(16) bf16_t Hs[64 * 264];
    const int tid = threadIdx.x;

    if (blockIdx.x >= 128) {
        // ---- M-build: j = (b-128)*2 + (tid>>8), col = tid&255 ----
        u64* bits = (u64*)Xs;                      // 8 KB alias
        const int jb = (blockIdx.x - 128) * 2;
#pragma unroll
        for (int p = 0; p < 2; p++) {
            const int idx = p * 512 + tid;
            bits[idx] = rowbits[idx];
        }
        __syncthreads();
        const int sub = tid >> 8, col = tid & 255;
        const int j = jb + sub;
        const int w64 = col >> 6, sh = col & 63;   // w64 wave-uniform
        int cnt = 0;
#pragma unroll 8
        for (int jp = 0; jp < 256; jp++)
            cnt += (int)((bits[jp * 4 + w64] >> sh) & 1ull);
        const int rc = (int)(__popcll(bits[j * 4 + 0]) + __popcll(bits[j * 4 + 1]) +
                             __popcll(bits[j * 4 + 2]) + __popcll(bits[j * 4 + 3]));
        const float rso = rsqrtf((float)(rc < 1 ? 1 : rc));
        const float rsi = rsqrtf((float)(cnt < 1 ? 1 : cnt));
        float g = 1.0f / (1.0f + expf(-gp[j * 256 + col]));
        if (col == j) g = 1.0f;
        if ((*iterp) > 50 && !(g > 0.1f)) g = 0.0f;
        if (adjOut) adjOut[j * 256 + col] = g;
        Mb[col * 256 + j] = (bf16_t)(g * rso * rsi);
        return;
    }

    // ---- encoder: 64-row band ----
    const bf16_t* Bte = Wt;
    const bf16_t* Btm = Wt + 65536;
    const bf16_t* Btl = Wt + 131072;
    const int r0 = blockIdx.x * 64;
    const int w = tid >> 6;
    const int lane = tid & 63;
    const int n = lane & 15, q = lane >> 4;
    const int cw = w * 32;
    const floatx4 z4 = {0.f, 0.f, 0.f, 0.f};

#pragma unroll
    for (int p = 0; p < 4; p++) {
        const int e0 = (p * 512 + tid) * 8;
        const int row = e0 >> 8, col = e0 & 255;
        *(bf16x8*)(Xs + row * 264 + col) = cvt8(X + (r0 + row) * 256 + col);
    }
    __syncthreads();

    // phase A: H = relu(Xs @ We + be)
    floatx4 ah[4][2];
#pragma unroll
    for (int rt = 0; rt < 4; rt++)
#pragma unroll
        for (int tc = 0; tc < 2; tc++) ah[rt][tc] = z4;
#pragma unroll 2
    for (int k0 = 0; k0 < 256; k0 += 32) {
        bf16x8 a[4], b[2];
#pragma unroll
        for (int rt = 0; rt < 4; rt++)
            a[rt] = *(const bf16x8*)(Xs + (rt * 16 + n) * 264 + k0 + q * 8);
#pragma unroll
        for (int tc = 0; tc < 2; tc++)
            b[tc] = *(const bf16x8*)(Bte + (cw + tc * 16 + n) * 256 + k0 + q * 8);
#pragma unroll
        for (int rt = 0; rt < 4; rt++)
#pragma unroll
            for (int tc = 0; tc < 2; tc++)
                ah[rt][tc] = MFMA16(a[rt], b[tc], ah[rt][tc]);
    }
#pragma unroll
    for (int tc = 0; tc < 2; tc++) {
        const int col = cw + tc * 16 + n;
        const float bv = benc[col];
#pragma unroll
        for (int rt = 0; rt < 4; rt++)
#pragma unroll
            for (int r = 0; r < 4; r++)
                Hs[(rt * 16 + q * 4 + r) * 264 + col] =
                    (bf16_t)fmaxf(ah[rt][tc][r] + bv, 0.0f);
    }
    __syncthreads();

    // phase B: mu & lv in ONE interleaved k-loop (16 MFMA/step)
    {
        floatx4 am[4][2], al[4][2];
#pragma unroll
        for (int rt = 0; rt < 4; rt++)
#pragma unroll
            for (int tc = 0; tc < 2; tc++) { am[rt][tc] = z4; al[rt][tc] = z4; }
#pragma unroll 2
        for (int k0 = 0; k0 < 256; k0 += 32) {
            bf16x8 a[4], bm_[2], bl_[2];
#pragma unroll
            for (int rt = 0; rt < 4; rt++)
                a[rt] = *(const bf16x8*)(Hs + (rt * 16 + n) * 264 + k0 + q * 8);
#pragma unroll
            for (int tc = 0; tc < 2; tc++) {
                bm_[tc] = *(const bf16x8*)(Btm + (cw + tc * 16 + n) * 256 + k0 + q * 8);
                bl_[tc] = *(const bf16x8*)(Btl + (cw + tc * 16 + n) * 256 + k0 + q * 8);
            }
#pragma unroll
            for (int rt = 0; rt < 4; rt++)
#pragma unroll
                for (int tc = 0; tc < 2; tc++) {
                    am[rt][tc] = MFMA16(a[rt], bm_[tc], am[rt][tc]);
                    al[rt][tc] = MFMA16(a[rt], bl_[tc], al[rt][tc]);
                }
        }
#pragma unroll
        for (int tc = 0; tc < 2; tc++) {
            const int col = cw + tc * 16 + n;
            const float bmv = bmu[col], blvv = blv[col];
#pragma unroll
            for (int rt = 0; rt < 4; rt++)
#pragma unroll
                for (int r = 0; r < 4; r++) {
                    const int row = r0 + rt * 16 + q * 4 + r;
                    MuOut[row * 256 + col] = am[rt][tc][r] + bmv;
                    LvOut[row * 256 + col] = al[rt][tc][r] + blvv;
                }
        }
    }
}

// ---------------------------------------------------------------------------
// K4: fused GCN v11 — round-9/11/13 verified version (77.5us).
// 2048 blocks x 512 thr, 4 batch rows/block, monolithic.
// Spill invariant: WRITE_SIZE == 8192 KB.
// ---------------------------------------------------------------------------
__global__ __launch_bounds__(512, 4) void k_gcn(
    const float* __restrict__ Mu, const float* __restrict__ Lv,
    const float* __restrict__ Eps, const bf16_t* __restrict__ wepack,
    const bf16_t* __restrict__ bepack, const float* __restrict__ Wg1,
    const float* __restrict__ bg1, const float* __restrict__ Wg2,
    const bf16_t* __restrict__ Mb, float* __restrict__ Vout) {
    __shared__ __align__(16) bf16_t smem[128 * 256];   // 64 KB: 4 bl x 32 e
    __shared__ float zs[1024];
    const int tid = threadIdx.x;
    const int lane = tid & 63;
    const int w = tid >> 6;                 // wave 0..7
    const int n = lane & 15, q = lane >> 4;
    const int bg = blockIdx.x;              // batch quad
    const floatx4 z4 = {0.f, 0.f, 0.f, 0.f};

    // stage z for 4 rows (coalesced fp32 reads, 2 elems/thread)
    {
        const int gi = bg * 1024 + tid;
        zs[tid] = fmaf(Eps[gi], __expf(0.5f * Lv[gi]), Mu[gi]);
        const int gi2 = gi + 512;
        zs[tid + 512] = fmaf(Eps[gi2], __expf(0.5f * Lv[gi2]), Mu[gi2]);
    }

    // preload W_g1 B-fragments
    bf16x8 wg1f[2][2];
#pragma unroll
    for (int ks = 0; ks < 2; ks++)
#pragma unroll
        for (int te = 0; te < 2; te++)
#pragma unroll
            for (int j = 0; j < 8; j++)
                wg1f[ks][te][j] = (bf16_t)Wg1[(ks * 32 + q * 8 + j) * 32 + te * 16 + n];
    __syncthreads();

    // ---- phase 1: wave w -> j-tiles {2w, 2w+1}, each for bl 0..3 ----
#pragma unroll
    for (int jt2 = 0; jt2 < 2; jt2++) {
        const int j0 = (w * 2 + jt2) * 16;
        const int jA = j0 + n;
        const bf16x8 we0 = *(const bf16x8*)(wepack + jA * 64 + q * 8);
        const bf16x8 we1 = *(const bf16x8*)(wepack + jA * 64 + 32 + q * 8);
        const bf16x8 be0 = *(const bf16x8*)(bepack + jA * 64 + q * 8);
        const bf16x8 be1 = *(const bf16x8*)(bepack + jA * 64 + 32 + q * 8);
        float wf0[8], wf1[8], bf0[8], bf1[8];
#pragma unroll
        for (int j = 0; j < 8; j++) {
            wf0[j] = (float)we0[j]; wf1[j] = (float)we1[j];
            bf0[j] = (float)be0[j]; bf1[j] = (float)be1[j];
        }
        const int j8a = (j0 >> 3) + (q >> 1);
        const int jlo = (q & 1) * 4;
        const int sw = ((j8a ^ (n & 7)) << 3) + jlo;
#pragma unroll
        for (int bl = 0; bl < 4; bl++) {
            const float zv = zs[bl * 256 + jA];   // 2log2e folded into packs
            bf16x8 a0, a1;
#pragma unroll
            for (int j = 0; j < 8; j++) {
                a0[j] = (bf16_t)fast_tanh2(fmaf(zv, wf0[j], bf0[j]));
                a1[j] = (bf16_t)fast_tanh2(fmaf(zv, wf1[j], bf1[j]));
            }
            floatx4 c0 = z4, c1 = z4;
            c0 = MFMA16(a0, wg1f[0][0], c0);
            c0 = MFMA16(a1, wg1f[1][0], c0);
            c1 = MFMA16(a0, wg1f[0][1], c1);
            c1 = MFMA16(a1, wg1f[1][1], c1);
            bf16x4 s0, s1;
#pragma unroll
            for (int r = 0; r < 4; r++) { s0[r] = (bf16_t)c0[r]; s1[r] = (bf16_t)c1[r]; }
            *(bf16x4*)(smem + (bl * 32 + n) * 256 + sw) = s0;        // e = n
            *(bf16x4*)(smem + (bl * 32 + 16 + n) * 256 + sw) = s1;   // e = 16+n
        }
    }
    __syncthreads();

    // ---- phase 2: T1 = M @ Q (wave w: i in [w*32,w*32+32), c in [0,128)) --
    const int i0 = w * 32;
    floatx4 acc[2][8];
#pragma unroll
    for (int ti = 0; ti < 2; ti++)
#pragma unroll
        for (int tc = 0; tc < 8; tc++) acc[ti][tc] = z4;
#pragma unroll
    for (int k0 = 0; k0 < 256; k0 += 32) {
        const int k8 = k0 >> 3;
        bf16x8 a[2], b[8];
#pragma unroll
        for (int ti = 0; ti < 2; ti++)
            a[ti] = *(const bf16x8*)(Mb + (i0 + ti * 16 + n) * 256 + k0 + q * 8);
#pragma unroll
        for (int tc = 0; tc < 8; tc++)
            b[tc] = *(const bf16x8*)(smem + (tc * 16 + n) * 256 +
                                     (((k8 + q) ^ (n & 7)) << 3));
        __builtin_amdgcn_s_setprio(1);
#pragma unroll
        for (int ti = 0; ti < 2; ti++)
#pragma unroll
            for (int tc = 0; tc < 8; tc++)
                acc[ti][tc] = MFMA16(a[ti], b[tc], acc[ti][tc]);
        __builtin_amdgcn_s_setprio(0);
    }

    // ---- epilogue: in-register relu+Wg2 contraction + reduce-scatter ----
    const float w2a = Wg2[n],      w2b = Wg2[16 + n];
    const float b1a = bg1[n],      b1b = bg1[16 + n];
    float v32[32];   // k = bl*8 + ti*4 + r
#pragma unroll
    for (int bl = 0; bl < 4; bl++)
#pragma unroll
        for (int ti = 0; ti < 2; ti++)
#pragma unroll
            for (int r = 0; r < 4; r++)
                v32[bl * 8 + ti * 4 + r] =
                    fmaxf(acc[ti][2 * bl][r] + b1a, 0.0f) * w2a +
                    fmaxf(acc[ti][2 * bl + 1][r] + b1b, 0.0f) * w2b;
    const bool h0 = (lane & 1), h1_ = (lane & 2), h2 = (lane & 4), h3 = (lane & 8);
    float u16[16];
#pragma unroll
    for (int p = 0; p < 16; p++) {
        const float keep = h0 ? v32[2 * p + 1] : v32[2 * p];
        const float send = h0 ? v32[2 * p] : v32[2 * p + 1];
        u16[p] = keep + __shfl_xor(send, 1, 64);
    }
    float u8[8];
#pragma unroll
    for (int p = 0; p < 8; p++) {
        const float keep = h1_ ? u16[2 * p + 1] : u16[2 * p];
        const float send = h1_ ? u16[2 * p] : u16[2 * p + 1];
        u8[p] = keep + __shfl_xor(send, 2, 64);
    }
    float u4[4];
#pragma unroll
    for (int p = 0; p < 4; p++) {
        const float keep = h2 ? u8[2 * p + 1] : u8[2 * p];
        const float send = h2 ? u8[2 * p] : u8[2 * p + 1];
        u4[p] = keep + __shfl_xor(send, 4, 64);
    }
    float u2[2];
#pragma unroll
    for (int p = 0; p < 2; p++) {
        const float keep = h3 ? u4[2 * p + 1] : u4[2 * p];
        const float send = h3 ? u4[2 * p] : u4[2 * p + 1];
        u2[p] = keep + __shfl_xor(send, 8, 64);
    }
    {
        // lane holds k = 16*p + n: r = n&3, ti = (n>>2)&1, bl = p*2 + (n>>3)
        const int i_out = i0 + ((n >> 2) & 1) * 16 + q * 4 + (n & 3);
        const int blv = n >> 3;
        Vout[bg * 1024 + blv * 256 + i_out] = u2[0];
        Vout[bg * 1024 + (2 + blv) * 256 + i_out] = u2[1];
    }
}

// ---------------------------------------------------------------------------
// K5: x_hat = V @ M^T + b_g2, in place.  256 blocks, 32-row bands (round-8
// verified shape; 128x64 left half the CUs idle for this small kernel).
// ---------------------------------------------------------------------------
__global__ __launch_bounds__(512) void k_out(
    float* __restrict__ VX, const bf16_t* __restrict__ Mb,
    const float* __restrict__ bg2) {
    __shared__ __align__(16) bf16_t va[32 * 264];
    const int tid = threadIdx.x;
    const int lane = tid & 63;
    const int w = tid >> 6;                 // wave 0..7 -> col group
    const int n = lane & 15, q = lane >> 4;
    const int r0 = blockIdx.x * 32;

#pragma unroll
    for (int p = 0; p < 4; p++) {
        const int i4 = p * 512 + tid;
        const int row = i4 >> 6, c4 = (i4 & 63) * 4;
        const floatx4 v = *(const floatx4*)(VX + (r0 + row) * 256 + c4);
        bf16x4 s;
#pragma unroll
        for (int r = 0; r < 4; r++) s[r] = (bf16_t)v[r];
        *(bf16x4*)(va + row * 264 + c4) = s;
    }
    __syncthreads();

    const int cw = w * 32;
    const floatx4 z4 = {0.f, 0.f, 0.f, 0.f};
    floatx4 acc[2][2];
#pragma unroll
    for (int rt = 0; rt < 2; rt++)
#pragma unroll
        for (int tc = 0; tc < 2; tc++) acc[rt][tc] = z4;
#pragma unroll 2
    for (int k0 = 0; k0 < 256; k0 += 32) {
        bf16x8 a[2], b[2];
#pragma unroll
        for (int rt = 0; rt < 2; rt++)
            a[rt] = *(const bf16x8*)(va + (rt * 16 + n) * 264 + k0 + q * 8);
#pragma unroll
        for (int tc = 0; tc < 2; tc++)
            b[tc] = *(const bf16x8*)(Mb + (cw + tc * 16 + n) * 256 + k0 + q * 8);
#pragma unroll
        for (int rt = 0; rt < 2; rt++)
#pragma unroll
            for (int tc = 0; tc < 2; tc++)
                acc[rt][tc] = MFMA16(a[rt], b[tc], acc[rt][tc]);
    }
    const float bv = bg2[0];
#pragma unroll
    for (int tc = 0; tc < 2; tc++) {
        const int col = cw + tc * 16 + n;
#pragma unroll
        for (int rt = 0; rt < 2; rt++)
#pragma unroll
            for (int r = 0; r < 4; r++)
                VX[(r0 + rt * 16 + q * 4 + r) * 256 + col] = acc[rt][tc][r] + bv;
    }
}

// ---------------------------------------------------------------------------
// K6: restore the real adjacency (fp32) — fallback path only (no d_ws).
// ---------------------------------------------------------------------------
__global__ __launch_bounds__(256) void k_adj(
    const float* __restrict__ gp, const int* __restrict__ iterp,
    float* __restrict__ adjOut) {
    const int o = blockIdx.x * 256 + threadIdx.x;  // o = j*256 + i
    const int j = o >> 8, i = o & 255;
    float g = 1.0f / (1.0f + expf(-gp[o]));
    if (i == j) g = 1.0f;
    if ((*iterp) > 50 && !(g > 0.1f)) g = 0.0f;
    adjOut[o] = g;
}

// ---------------------------------------------------------------------------
extern "C" void kernel_launch(void* const* d_in, const int* in_sizes, int n_in,
                              void* d_out, int out_size, void* d_ws, size_t ws_size,
                              hipStream_t stream) {
    const float* x    = (const float*)d_in[0];
    const float* eps  = (const float*)d_in[1];
    const float* Wenc = (const float*)d_in[2];
    const float* benc = (const float*)d_in[3];
    const float* Wmu  = (const float*)d_in[4];
    const float* bmu  = (const float*)d_in[5];
    const float* Wlv  = (const float*)d_in[6];
    const float* blv  = (const float*)d_in[7];
    const float* gp   = (const float*)d_in[8];
    const float* Wemb = (const float*)d_in[9];
    const float* bemb = (const float*)d_in[10];
    const float* Wg1  = (const float*)d_in[11];
    const float* bg1  = (const float*)d_in[12];
    const float* Wg2  = (const float*)d_in[13];
    const float* bg2  = (const float*)d_in[14];
    const int*   itr  = (const int*)d_in[15];
    (void)in_sizes; (void)n_in; (void)out_size;

    float* xhat = (float*)d_out;             // [8192,256] fp32
    float* adjO = xhat + ADJ_OFF;            // [256,256]  fp32
    float* muo  = xhat + MU_OFF;             // [8192,256] fp32
    float* lvo  = xhat + LV_OFF;             // [8192,256] fp32

    // Scratch: Mb [0,128K) | wepack [128K,160K) | bepack [160K,192K) |
    // rowbits [192K,200K).  Primary: d_ws (adj slot free from the start ->
    // k_mid writes adjO, no k_adj).  Fallback: adj slot + k_adj last.
    // Wt (384 KB) at xhat byte 4 MB: dead after k_mid.
    const bool usews = (d_ws != nullptr && ws_size >= 262144);
    char* scr = usews ? (char*)d_ws : (char*)adjO;
    bf16_t* Mb      = (bf16_t*)scr;
    bf16_t* wepack  = (bf16_t*)(scr + 131072);
    bf16_t* bepack  = (bf16_t*)(scr + 163840);
    u64*    rowbits = (u64*)(scr + 196608);
    bf16_t* Wt      = (bf16_t*)((char*)d_out + 4194304);

    k_prep<<<dim3(464), dim3(256), 0, stream>>>(Wenc, Wmu, Wlv, Wemb, bemb,
                                                gp, itr, Wt, wepack, bepack,
                                                rowbits);
    k_mid <<<dim3(256), dim3(512), 0, stream>>>(x, Wt, benc, bmu, blv, muo,
                                                lvo, gp, itr, rowbits, Mb,
                                                usews ? adjO : nullptr);
    k_gcn <<<dim3(2048), dim3(512), 0, stream>>>(muo, lvo, eps, wepack, bepack,
                                                 Wg1, bg1, Wg2, Mb, xhat);
    k_out <<<dim3(256), dim3(512), 0, stream>>>(xhat, Mb, bg2);
    if (!usews)
        k_adj<<<dim3(256), dim3(256), 0, stream>>>(gp, itr, adjO);
}